// Round 9
// baseline (209.977 us; speedup 1.0000x reference)
//
#include <hip/hip_runtime.h>
#include <math.h>

#define NROW 1024
#define BATCH 4
#define NT 16
#define NTRI 136             // 16*17/2
#define NBLK (BATCH * NTRI)  // 544
#define NPROD 256
#define PROD_ROWS 16
#define NROWS_TOT 4096

__device__ __forceinline__ float tanh_fast(float x) {
    const float e = __expf(2.f * fabsf(x));
    const float r = 1.f - 2.f / (e + 1.f);
    return copysignf(r, x);
}

// ---------------------------------------------------------------------------
// Producer-consumer single dispatch. Looped (I$-resident) pair-phase k-loop,
// but ALL accumulator indexing static -> F/G/S stay in VGPRs (r7 post-mortem:
// a runtime-indexed epilogue demoted them to scratch, rule #20).
// ---------------------------------------------------------------------------
__global__ __launch_bounds__(256) void pc_scorer(
    const float* __restrict__ emb,   // [4096][128]
    const float* __restrict__ temp,  // [4096][64]
    const float* __restrict__ W1,    // [192][64]
    const float* __restrict__ b1,    // [64]
    const float* __restrict__ W2,    // [64][32]
    const float* __restrict__ b2,    // [32]
    const float* __restrict__ W3,    // [64][32]
    const float* __restrict__ b3,    // [32]
    const float* __restrict__ W4,    // [32]
    const float* __restrict__ b4,    // [1]
    float* __restrict__ out,         // [4][1024][1024]
    float* __restrict__ hiS,         // [4096][32] scratch
    float* __restrict__ hjbS,        // [4096][32] scratch
    unsigned* __restrict__ cnt)      // [1] scratch, memset to 0 on stream
{
    __shared__ __align__(16) float smem[4 * 32 * 68];
    float* FT = smem;
    float* X  = smem;         // [16][192]
    float* H  = smem + 3072;  // [16][64]
    float* P  = smem + 4096;  // [16][32]

    const int t = threadIdx.x;
    const int bx = blockIdx.x;

    // ================= producer phase (blocks 0..255) =================
    if (bx < NPROD) {
        const int rowbase = bx * PROD_ROWS;

#pragma unroll
        for (int rep = 0; rep < 3; ++rep) {
            const int idx = t + rep * 256;  // 0..767
            const int r = idx / 48;
            const int c = idx - r * 48;
            float4 v;
            if (c < 32) v = reinterpret_cast<const float4*>(emb)[(size_t)(rowbase + r) * 32 + c];
            else        v = reinterpret_cast<const float4*>(temp)[(size_t)(rowbase + r) * 16 + (c - 32)];
            *reinterpret_cast<float4*>(&X[r * 192 + c * 4]) = v;
        }
        __syncthreads();

        // L1: [16x192]@[192x64]+b1 -> relu -> H (4 independent rows/thread)
        {
            const int o = t & 63;
            const int r0 = t >> 6;  // 0..3
            float s0 = b1[o], s1 = s0, s2 = s0, s3 = s0;
#pragma unroll 4
            for (int k4 = 0; k4 < 48; ++k4) {
                const float4 x0 = *reinterpret_cast<const float4*>(&X[r0 * 192 + k4 * 4]);
                const float4 x1 = *reinterpret_cast<const float4*>(&X[(r0 + 4) * 192 + k4 * 4]);
                const float4 x2 = *reinterpret_cast<const float4*>(&X[(r0 + 8) * 192 + k4 * 4]);
                const float4 x3 = *reinterpret_cast<const float4*>(&X[(r0 + 12) * 192 + k4 * 4]);
                const float w0 = W1[(k4 * 4 + 0) * 64 + o];
                const float w1 = W1[(k4 * 4 + 1) * 64 + o];
                const float w2 = W1[(k4 * 4 + 2) * 64 + o];
                const float w3 = W1[(k4 * 4 + 3) * 64 + o];
                s0 = fmaf(x0.w, w3, fmaf(x0.z, w2, fmaf(x0.y, w1, fmaf(x0.x, w0, s0))));
                s1 = fmaf(x1.w, w3, fmaf(x1.z, w2, fmaf(x1.y, w1, fmaf(x1.x, w0, s1))));
                s2 = fmaf(x2.w, w3, fmaf(x2.z, w2, fmaf(x2.y, w1, fmaf(x2.x, w0, s2))));
                s3 = fmaf(x3.w, w3, fmaf(x3.z, w2, fmaf(x3.y, w1, fmaf(x3.x, w0, s3))));
            }
            H[r0 * 64 + o]        = fmaxf(s0, 0.f);
            H[(r0 + 4) * 64 + o]  = fmaxf(s1, 0.f);
            H[(r0 + 8) * 64 + o]  = fmaxf(s2, 0.f);
            H[(r0 + 12) * 64 + o] = fmaxf(s3, 0.f);
        }
        __syncthreads();

        // L2: [16x64]@[64x32]+b2 -> relu -> P (2 rows/thread)
        {
            const int o2 = t & 31;
            const int r8 = t >> 5;  // 0..7
#pragma unroll
            for (int rr = 0; rr < 2; ++rr) {
                const int r = r8 + rr * 8;
                float s = b2[o2];
#pragma unroll 8
                for (int k = 0; k < 64; ++k) s += H[r * 64 + k] * W2[k * 32 + o2];
                P[r * 32 + o2] = fmaxf(s, 0.f);
            }
        }
        __syncthreads();

        // L3: hi = P@W3[:32]; hjb = P@W3[32:]+b3 -> global scratch
        {
            const int o2 = t & 31;
            const int r8 = t >> 5;
#pragma unroll
            for (int rr = 0; rr < 2; ++rr) {
                const int r = r8 + rr * 8;
                float sa = 0.f, sb = b3[o2];
#pragma unroll 8
                for (int k = 0; k < 32; ++k) {
                    const float p = P[r * 32 + k];
                    sa += p * W3[k * 32 + o2];
                    sb += p * W3[(32 + k) * 32 + o2];
                }
                hiS[(size_t)(rowbase + r) * 32 + o2] = sa;
                hjbS[(size_t)(rowbase + r) * 32 + o2] = sb;
            }
        }
        __syncthreads();
        if (t == 0) {
            __threadfence();
            __hip_atomic_fetch_add(cnt, 1u, __ATOMIC_RELEASE, __HIP_MEMORY_SCOPE_AGENT);
        }
    }

    // ================= one-way barrier: wait for all 256 producers ===========
    if (t == 0) {
        while (__hip_atomic_load(cnt, __ATOMIC_ACQUIRE, __HIP_MEMORY_SCOPE_AGENT) < NPROD)
            __builtin_amdgcn_s_sleep(2);
    }
    __syncthreads();

    // ================= consumer: stage feature tiles transposed ==============
    const int b = bx / NTRI;
    int tidx = bx % NTRI;
    int ti = 0;
    while (tidx >= NT - ti) { tidx -= NT - ti; ++ti; }
    const int tj = ti + tidx;

    {
        const float* hiB  = hiS + (size_t)b * (NROW * 32);
        const float* hjbB = hjbS + (size_t)b * (NROW * 32);
#pragma unroll
        for (int rep = 0; rep < 2; ++rep) {
            const int idx = t + rep * 256;  // 0..511
            const int r = idx >> 3, k4 = idx & 7;
            float4 v0 = reinterpret_cast<const float4*>(hiB)[(ti * 64 + r) * 8 + k4];   // hi  I
            float4 v1 = reinterpret_cast<const float4*>(hjbB)[(tj * 64 + r) * 8 + k4];  // hjb J
            float4 v2 = reinterpret_cast<const float4*>(hiB)[(tj * 64 + r) * 8 + k4];   // hi  J
            float4 v3 = reinterpret_cast<const float4*>(hjbB)[(ti * 64 + r) * 8 + k4];  // hjb I
            FT[(0 * 32 + k4 * 4 + 0) * 68 + r] = v0.x; FT[(0 * 32 + k4 * 4 + 1) * 68 + r] = v0.y;
            FT[(0 * 32 + k4 * 4 + 2) * 68 + r] = v0.z; FT[(0 * 32 + k4 * 4 + 3) * 68 + r] = v0.w;
            FT[(3 * 32 + k4 * 4 + 0) * 68 + r] = v1.x; FT[(3 * 32 + k4 * 4 + 1) * 68 + r] = v1.y;
            FT[(3 * 32 + k4 * 4 + 2) * 68 + r] = v1.z; FT[(3 * 32 + k4 * 4 + 3) * 68 + r] = v1.w;
            FT[(2 * 32 + k4 * 4 + 0) * 68 + r] = v2.x; FT[(2 * 32 + k4 * 4 + 1) * 68 + r] = v2.y;
            FT[(2 * 32 + k4 * 4 + 2) * 68 + r] = v2.z; FT[(2 * 32 + k4 * 4 + 3) * 68 + r] = v2.w;
            FT[(1 * 32 + k4 * 4 + 0) * 68 + r] = v3.x; FT[(1 * 32 + k4 * 4 + 1) * 68 + r] = v3.y;
            FT[(1 * 32 + k4 * 4 + 2) * 68 + r] = v3.z; FT[(1 * 32 + k4 * 4 + 3) * 68 + r] = v3.w;
        }
    }
    __syncthreads();

    // ============ pair phase: looped k (I$-resident), static reg indexing =====
    const int ty = t >> 4;  // 0..15
    const int tx = t & 15;  // 0..15

    float F[4][4] = {};  // pre-act of z(i0+a, j0+c)   -- registers (static idx)
    float G[4][4] = {};  // pre-act of z(j0+c, i0+a)

    const float* ftI = &FT[4 * ty];  // k stride 68 floats
    const float* ftJ = &FT[4 * tx];

#pragma unroll 1
    for (int k4 = 0; k4 < 8; ++k4) {
        const float4 w4 = reinterpret_cast<const float4*>(W4)[k4];
        const float wreg[4] = {w4.x, w4.y, w4.z, w4.w};
#pragma unroll
        for (int kk = 0; kk < 4; ++kk) {
            const int k = k4 * 4 + kk;
            const float w = wreg[kk];
            const float4 ai = *reinterpret_cast<const float4*>(ftI + (0 * 32 + k) * 68);  // hi  I
            const float4 bi = *reinterpret_cast<const float4*>(ftI + (1 * 32 + k) * 68);  // hjb I
            const float4 aj = *reinterpret_cast<const float4*>(ftJ + (2 * 32 + k) * 68);  // hi  J
            const float4 bj = *reinterpret_cast<const float4*>(ftJ + (3 * 32 + k) * 68);  // hjb J
            const float av[4] = {ai.x, ai.y, ai.z, ai.w};
            const float bw[4] = {bi.x, bi.y, bi.z, bi.w};
            const float aw[4] = {aj.x, aj.y, aj.z, aj.w};
            const float bv[4] = {bj.x, bj.y, bj.z, bj.w};
#pragma unroll
            for (int a = 0; a < 4; ++a)
#pragma unroll
                for (int c = 0; c < 4; ++c) {
                    F[a][c] = fmaf(fmaxf(av[a] + bv[c], 0.f), w, F[a][c]);
                    G[a][c] = fmaf(fmaxf(aw[c] + bw[a], 0.f), w, G[a][c]);
                }
        }
    }

    // epilogue: FULLY unrolled -> S/F/G statically indexed, stay in VGPRs
    const float bb = *b4;
    float S[4][4];
#pragma unroll
    for (int a = 0; a < 4; ++a)
#pragma unroll
        for (int c = 0; c < 4; ++c)
            S[a][c] = 0.5f * (tanh_fast(F[a][c] + bb) + tanh_fast(G[a][c] + bb));

    float* outb = out + (size_t)b * (NROW * NROW);
    const int i0 = ti * 64 + 4 * ty;
    const int j0 = tj * 64 + 4 * tx;
#pragma unroll
    for (int a = 0; a < 4; ++a) {
        float4 v = make_float4(S[a][0], S[a][1], S[a][2], S[a][3]);
        *reinterpret_cast<float4*>(&outb[(size_t)(i0 + a) * NROW + j0]) = v;
    }
    if (ti != tj) {
#pragma unroll
        for (int c = 0; c < 4; ++c) {
            float4 v = make_float4(S[0][c], S[1][c], S[2][c], S[3][c]);
            *reinterpret_cast<float4*>(&outb[(size_t)(j0 + c) * NROW + i0]) = v;
        }
    }
}

// ---------------------------------------------------------------------------
// Fallback (ws too small): round-4 kernel, known-good at 229us.
// ---------------------------------------------------------------------------
__global__ __launch_bounds__(256) void fused_fallback(
    const float* __restrict__ emb, const float* __restrict__ temp,
    const float* __restrict__ W1, const float* __restrict__ b1,
    const float* __restrict__ W2, const float* __restrict__ b2,
    const float* __restrict__ W3, const float* __restrict__ b3,
    const float* __restrict__ W4, const float* __restrict__ b4,
    float* __restrict__ out)
{
    __shared__ __align__(16) float FT[4][32][68];
    __shared__ __align__(16) float X[16][192];
    __shared__ __align__(16) float H[16][64];
    __shared__ __align__(16) float P[16][32];

    const int t = threadIdx.x;
    const int bx = blockIdx.x;
    const int b = bx / NTRI;
    int tidx = bx % NTRI;
    int ti = 0;
    while (tidx >= NT - ti) { tidx -= NT - ti; ++ti; }
    const int tj = ti + tidx;

    for (int ch = 0; ch < 8; ++ch) {
        const int tile = (ch < 4) ? ti : tj;
        const int sub = ch & 3;
        const int half = ch >> 2;
        const int rowbase = b * NROW + tile * 64 + sub * 16;
#pragma unroll
        for (int rep = 0; rep < 3; ++rep) {
            const int idx = t + rep * 256;
            const int r = idx / 48;
            const int c = idx - r * 48;
            float4 v;
            if (c < 32) v = reinterpret_cast<const float4*>(emb)[(size_t)(rowbase + r) * 32 + c];
            else        v = reinterpret_cast<const float4*>(temp)[(size_t)(rowbase + r) * 16 + (c - 32)];
            *reinterpret_cast<float4*>(&X[r][c * 4]) = v;
        }
        __syncthreads();
        {
            const int o = t & 63;
            const int r0 = t >> 6;
            float s0 = b1[o], s1 = s0, s2 = s0, s3 = s0;
#pragma unroll 4
            for (int k4 = 0; k4 < 48; ++k4) {
                const float4 x0 = *reinterpret_cast<const float4*>(&X[r0][k4 * 4]);
                const float4 x1 = *reinterpret_cast<const float4*>(&X[r0 + 4][k4 * 4]);
                const float4 x2 = *reinterpret_cast<const float4*>(&X[r0 + 8][k4 * 4]);
                const float4 x3 = *reinterpret_cast<const float4*>(&X[r0 + 12][k4 * 4]);
                const float w0 = W1[(k4 * 4 + 0) * 64 + o];
                const float w1 = W1[(k4 * 4 + 1) * 64 + o];
                const float w2 = W1[(k4 * 4 + 2) * 64 + o];
                const float w3 = W1[(k4 * 4 + 3) * 64 + o];
                s0 = fmaf(x0.w, w3, fmaf(x0.z, w2, fmaf(x0.y, w1, fmaf(x0.x, w0, s0))));
                s1 = fmaf(x1.w, w3, fmaf(x1.z, w2, fmaf(x1.y, w1, fmaf(x1.x, w0, s1))));
                s2 = fmaf(x2.w, w3, fmaf(x2.z, w2, fmaf(x2.y, w1, fmaf(x2.x, w0, s2))));
                s3 = fmaf(x3.w, w3, fmaf(x3.z, w2, fmaf(x3.y, w1, fmaf(x3.x, w0, s3))));
            }
            H[r0][o] = fmaxf(s0, 0.f);
            H[r0 + 4][o] = fmaxf(s1, 0.f);
            H[r0 + 8][o] = fmaxf(s2, 0.f);
            H[r0 + 12][o] = fmaxf(s3, 0.f);
        }
        __syncthreads();
        {
            const int o2 = t & 31;
            const int r8 = t >> 5;
#pragma unroll
            for (int rr = 0; rr < 2; ++rr) {
                const int r = r8 + rr * 8;
                float s = b2[o2];
#pragma unroll 8
                for (int k = 0; k < 64; ++k) s += H[r][k] * W2[k * 32 + o2];
                P[r][o2] = fmaxf(s, 0.f);
            }
        }
        __syncthreads();
        {
            const int o2 = t & 31;
            const int r8 = t >> 5;
#pragma unroll
            for (int rr = 0; rr < 2; ++rr) {
                const int r = r8 + rr * 8;
                float sa = 0.f, sb = b3[o2];
#pragma unroll 8
                for (int k = 0; k < 32; ++k) {
                    const float p = P[r][k];
                    sa += p * W3[k * 32 + o2];
                    sb += p * W3[(32 + k) * 32 + o2];
                }
                FT[half * 2 + 0][o2][sub * 16 + r] = sa;
                FT[half * 2 + 1][o2][sub * 16 + r] = sb;
            }
        }
        __syncthreads();
    }

    const int ty = t >> 4;
    const int tx = t & 15;
    float F[4][4] = {};
    float G[4][4] = {};
#pragma unroll 1
    for (int k = 0; k < 32; ++k) {
        const float w = W4[k];
        const float4 ai = *reinterpret_cast<const float4*>(&FT[0][k][4 * ty]);
        const float4 bi = *reinterpret_cast<const float4*>(&FT[1][k][4 * ty]);
        const float4 aj = *reinterpret_cast<const float4*>(&FT[2][k][4 * tx]);
        const float4 bj = *reinterpret_cast<const float4*>(&FT[3][k][4 * tx]);
        const float av[4] = {ai.x, ai.y, ai.z, ai.w};
        const float bw[4] = {bi.x, bi.y, bi.z, bi.w};
        const float aw[4] = {aj.x, aj.y, aj.z, aj.w};
        const float bv[4] = {bj.x, bj.y, bj.z, bj.w};
#pragma unroll
        for (int a = 0; a < 4; ++a)
#pragma unroll
            for (int c = 0; c < 4; ++c) {
                F[a][c] = fmaf(fmaxf(av[a] + bv[c], 0.f), w, F[a][c]);
                G[a][c] = fmaf(fmaxf(aw[c] + bw[a], 0.f), w, G[a][c]);
            }
    }
    const float bb = *b4;
    float S[4][4];
#pragma unroll
    for (int a = 0; a < 4; ++a)
#pragma unroll
        for (int c = 0; c < 4; ++c)
            S[a][c] = 0.5f * (tanh_fast(F[a][c] + bb) + tanh_fast(G[a][c] + bb));
    float* outb = out + (size_t)b * (NROW * NROW);
    const int i0 = ti * 64 + 4 * ty;
    const int j0 = tj * 64 + 4 * tx;
#pragma unroll
    for (int a = 0; a < 4; ++a) {
        float4 v = make_float4(S[a][0], S[a][1], S[a][2], S[a][3]);
        *reinterpret_cast<float4*>(&outb[(size_t)(i0 + a) * NROW + j0]) = v;
    }
    if (ti != tj) {
#pragma unroll
        for (int c = 0; c < 4; ++c) {
            float4 v = make_float4(S[0][c], S[1][c], S[2][c], S[3][c]);
            *reinterpret_cast<float4*>(&outb[(size_t)(j0 + c) * NROW + i0]) = v;
        }
    }
}

extern "C" void kernel_launch(void* const* d_in, const int* in_sizes, int n_in,
                              void* d_out, int out_size, void* d_ws, size_t ws_size,
                              hipStream_t stream) {
    const float* emb  = (const float*)d_in[0];
    const float* temp = (const float*)d_in[1];
    const float* W1   = (const float*)d_in[2];
    const float* b1   = (const float*)d_in[3];
    const float* W2   = (const float*)d_in[4];
    const float* b2   = (const float*)d_in[5];
    const float* W3   = (const float*)d_in[6];
    const float* b3   = (const float*)d_in[7];
    const float* W4   = (const float*)d_in[8];
    const float* b4   = (const float*)d_in[9];
    float* out = (float*)d_out;

    const size_t need = 16 + (size_t)2 * NROWS_TOT * 32 * sizeof(float);
    if (ws_size >= need) {
        unsigned* cnt = (unsigned*)d_ws;
        float* hiS  = (float*)((char*)d_ws + 16);
        float* hjbS = hiS + (size_t)NROWS_TOT * 32;
        hipMemsetAsync(d_ws, 0, 16, stream);
        hipLaunchKernelGGL(pc_scorer, dim3(NBLK), dim3(256), 0, stream,
                           emb, temp, W1, b1, W2, b2, W3, b3, W4, b4, out,
                           hiS, hjbS, cnt);
    } else {
        hipLaunchKernelGGL(fused_fallback, dim3(NBLK), dim3(256), 0, stream,
                           emb, temp, W1, b1, W2, b2, W3, b3, W4, b4, out);
    }
}

// Round 11
// 50.144 us; speedup vs baseline: 4.1875x; 4.1875x over previous
//
#include <hip/hip_runtime.h>
#include <math.h>

#define NROW 1024
#define BATCH 4
#define NT 16
#define NTRI 136             // 16*17/2
#define NBLK (BATCH * NTRI)  // 544
#define NPROD 256
#define PROD_ROWS 16
#define NROWS_TOT 4096

__device__ __forceinline__ float tanh_fast(float x) {
    const float e = __expf(2.f * fabsf(x));
    const float r = 1.f - 2.f / (e + 1.f);
    return copysignf(r, x);
}

// ---------------------------------------------------------------------------
// Dispatch A: feature producer (verbatim producer phase of the passing
// pc_scorer, rounds 6-9). 256 blocks x 256 threads, 16 rows each.
// ---------------------------------------------------------------------------
__global__ __launch_bounds__(256) void k_feat(
    const float* __restrict__ emb,   // [4096][128]
    const float* __restrict__ temp,  // [4096][64]
    const float* __restrict__ W1,    // [192][64]
    const float* __restrict__ b1,    // [64]
    const float* __restrict__ W2,    // [64][32]
    const float* __restrict__ b2,    // [32]
    const float* __restrict__ W3,    // [64][32]
    const float* __restrict__ b3,    // [32]
    float* __restrict__ hiS,         // [4096][32]
    float* __restrict__ hjbS)        // [4096][32]
{
    __shared__ __align__(16) float X[16 * 192];
    __shared__ __align__(16) float H[16 * 64];
    __shared__ __align__(16) float P[16 * 32];

    const int t = threadIdx.x;
    const int rowbase = blockIdx.x * PROD_ROWS;

#pragma unroll
    for (int rep = 0; rep < 3; ++rep) {
        const int idx = t + rep * 256;  // 0..767
        const int r = idx / 48;
        const int c = idx - r * 48;
        float4 v;
        if (c < 32) v = reinterpret_cast<const float4*>(emb)[(size_t)(rowbase + r) * 32 + c];
        else        v = reinterpret_cast<const float4*>(temp)[(size_t)(rowbase + r) * 16 + (c - 32)];
        *reinterpret_cast<float4*>(&X[r * 192 + c * 4]) = v;
    }
    __syncthreads();

    // L1: [16x192]@[192x64]+b1 -> relu -> H (4 independent rows/thread)
    {
        const int o = t & 63;
        const int r0 = t >> 6;  // 0..3
        float s0 = b1[o], s1 = s0, s2 = s0, s3 = s0;
#pragma unroll 4
        for (int k4 = 0; k4 < 48; ++k4) {
            const float4 x0 = *reinterpret_cast<const float4*>(&X[r0 * 192 + k4 * 4]);
            const float4 x1 = *reinterpret_cast<const float4*>(&X[(r0 + 4) * 192 + k4 * 4]);
            const float4 x2 = *reinterpret_cast<const float4*>(&X[(r0 + 8) * 192 + k4 * 4]);
            const float4 x3 = *reinterpret_cast<const float4*>(&X[(r0 + 12) * 192 + k4 * 4]);
            const float w0 = W1[(k4 * 4 + 0) * 64 + o];
            const float w1 = W1[(k4 * 4 + 1) * 64 + o];
            const float w2 = W1[(k4 * 4 + 2) * 64 + o];
            const float w3 = W1[(k4 * 4 + 3) * 64 + o];
            s0 = fmaf(x0.w, w3, fmaf(x0.z, w2, fmaf(x0.y, w1, fmaf(x0.x, w0, s0))));
            s1 = fmaf(x1.w, w3, fmaf(x1.z, w2, fmaf(x1.y, w1, fmaf(x1.x, w0, s1))));
            s2 = fmaf(x2.w, w3, fmaf(x2.z, w2, fmaf(x2.y, w1, fmaf(x2.x, w0, s2))));
            s3 = fmaf(x3.w, w3, fmaf(x3.z, w2, fmaf(x3.y, w1, fmaf(x3.x, w0, s3))));
        }
        H[r0 * 64 + o]        = fmaxf(s0, 0.f);
        H[(r0 + 4) * 64 + o]  = fmaxf(s1, 0.f);
        H[(r0 + 8) * 64 + o]  = fmaxf(s2, 0.f);
        H[(r0 + 12) * 64 + o] = fmaxf(s3, 0.f);
    }
    __syncthreads();

    // L2: [16x64]@[64x32]+b2 -> relu -> P (2 rows/thread)
    {
        const int o2 = t & 31;
        const int r8 = t >> 5;  // 0..7
#pragma unroll
        for (int rr = 0; rr < 2; ++rr) {
            const int r = r8 + rr * 8;
            float s = b2[o2];
#pragma unroll 8
            for (int k = 0; k < 64; ++k) s += H[r * 64 + k] * W2[k * 32 + o2];
            P[r * 32 + o2] = fmaxf(s, 0.f);
        }
    }
    __syncthreads();

    // L3: hi = P@W3[:32]; hjb = P@W3[32:]+b3 -> global scratch
    {
        const int o2 = t & 31;
        const int r8 = t >> 5;
#pragma unroll
        for (int rr = 0; rr < 2; ++rr) {
            const int r = r8 + rr * 8;
            float sa = 0.f, sb = b3[o2];
#pragma unroll 8
            for (int k = 0; k < 32; ++k) {
                const float p = P[r * 32 + k];
                sa += p * W3[k * 32 + o2];
                sb += p * W3[(32 + k) * 32 + o2];
            }
            hiS[(size_t)(rowbase + r) * 32 + o2] = sa;
            hjbS[(size_t)(rowbase + r) * 32 + o2] = sb;
        }
    }
}

// ---------------------------------------------------------------------------
// Dispatch B: pairwise consumer. 544 blocks x 256 threads. Staging + pair
// phase verbatim from the 75us round-5 kernel (fully-unrolled k-loop,
// fully-static register indexing).
// ---------------------------------------------------------------------------
__global__ __launch_bounds__(256) void k_pair(
    const float* __restrict__ hiS,   // [4096][32]
    const float* __restrict__ hjbS,  // [4096][32]
    const float* __restrict__ W4,    // [32]
    const float* __restrict__ b4,    // [1]
    float* __restrict__ out)         // [4][1024][1024]
{
    __shared__ __align__(16) float FT[4 * 32 * 68];

    const int t = threadIdx.x;
    const int bx = blockIdx.x;
    const int b = bx / NTRI;
    int tidx = bx % NTRI;
    int ti = 0;
    while (tidx >= NT - ti) { tidx -= NT - ti; ++ti; }
    const int tj = ti + tidx;

    {
        const float* hiB  = hiS + (size_t)b * (NROW * 32);
        const float* hjbB = hjbS + (size_t)b * (NROW * 32);
#pragma unroll
        for (int rep = 0; rep < 2; ++rep) {
            const int idx = t + rep * 256;  // 0..511
            const int r = idx >> 3, k4 = idx & 7;
            float4 v0 = reinterpret_cast<const float4*>(hiB)[(ti * 64 + r) * 8 + k4];   // hi  I
            float4 v1 = reinterpret_cast<const float4*>(hjbB)[(tj * 64 + r) * 8 + k4];  // hjb J
            float4 v2 = reinterpret_cast<const float4*>(hiB)[(tj * 64 + r) * 8 + k4];   // hi  J
            float4 v3 = reinterpret_cast<const float4*>(hjbB)[(ti * 64 + r) * 8 + k4];  // hjb I
            FT[(0 * 32 + k4 * 4 + 0) * 68 + r] = v0.x; FT[(0 * 32 + k4 * 4 + 1) * 68 + r] = v0.y;
            FT[(0 * 32 + k4 * 4 + 2) * 68 + r] = v0.z; FT[(0 * 32 + k4 * 4 + 3) * 68 + r] = v0.w;
            FT[(3 * 32 + k4 * 4 + 0) * 68 + r] = v1.x; FT[(3 * 32 + k4 * 4 + 1) * 68 + r] = v1.y;
            FT[(3 * 32 + k4 * 4 + 2) * 68 + r] = v1.z; FT[(3 * 32 + k4 * 4 + 3) * 68 + r] = v1.w;
            FT[(2 * 32 + k4 * 4 + 0) * 68 + r] = v2.x; FT[(2 * 32 + k4 * 4 + 1) * 68 + r] = v2.y;
            FT[(2 * 32 + k4 * 4 + 2) * 68 + r] = v2.z; FT[(2 * 32 + k4 * 4 + 3) * 68 + r] = v2.w;
            FT[(1 * 32 + k4 * 4 + 0) * 68 + r] = v3.x; FT[(1 * 32 + k4 * 4 + 1) * 68 + r] = v3.y;
            FT[(1 * 32 + k4 * 4 + 2) * 68 + r] = v3.z; FT[(1 * 32 + k4 * 4 + 3) * 68 + r] = v3.w;
        }
    }
    __syncthreads();

    const int ty = t >> 4;  // 0..15
    const int tx = t & 15;  // 0..15

    float F[4][4] = {};  // pre-act of z(i0+a, j0+c)
    float G[4][4] = {};  // pre-act of z(j0+c, i0+a)
#pragma unroll
    for (int k = 0; k < 32; ++k) {
        const float w = W4[k];
        const float4 ai = *reinterpret_cast<const float4*>(&FT[(0 * 32 + k) * 68 + 4 * ty]);  // hi  I
        const float4 bi = *reinterpret_cast<const float4*>(&FT[(1 * 32 + k) * 68 + 4 * ty]);  // hjb I
        const float4 aj = *reinterpret_cast<const float4*>(&FT[(2 * 32 + k) * 68 + 4 * tx]);  // hi  J
        const float4 bj = *reinterpret_cast<const float4*>(&FT[(3 * 32 + k) * 68 + 4 * tx]);  // hjb J
        const float av[4] = {ai.x, ai.y, ai.z, ai.w};
        const float bw[4] = {bi.x, bi.y, bi.z, bi.w};
        const float aw[4] = {aj.x, aj.y, aj.z, aj.w};
        const float bv[4] = {bj.x, bj.y, bj.z, bj.w};
#pragma unroll
        for (int a = 0; a < 4; ++a)
#pragma unroll
            for (int c = 0; c < 4; ++c) {
                F[a][c] = fmaf(fmaxf(av[a] + bv[c], 0.f), w, F[a][c]);
                G[a][c] = fmaf(fmaxf(aw[c] + bw[a], 0.f), w, G[a][c]);
            }
    }

    const float bb = *b4;
    float S[4][4];
#pragma unroll
    for (int a = 0; a < 4; ++a)
#pragma unroll
        for (int c = 0; c < 4; ++c)
            S[a][c] = 0.5f * (tanh_fast(F[a][c] + bb) + tanh_fast(G[a][c] + bb));

    float* outb = out + (size_t)b * (NROW * NROW);
    const int i0 = ti * 64 + 4 * ty;
    const int j0 = tj * 64 + 4 * tx;
#pragma unroll
    for (int a = 0; a < 4; ++a) {
        float4 v = make_float4(S[a][0], S[a][1], S[a][2], S[a][3]);
        *reinterpret_cast<float4*>(&outb[(size_t)(i0 + a) * NROW + j0]) = v;
    }
    if (ti != tj) {
#pragma unroll
        for (int c = 0; c < 4; ++c) {
            float4 v = make_float4(S[0][c], S[1][c], S[2][c], S[3][c]);
            *reinterpret_cast<float4*>(&outb[(size_t)(j0 + c) * NROW + i0]) = v;
        }
    }
}

// ---------------------------------------------------------------------------
// Fallback (ws too small): round-4 self-contained kernel, known-good @229us.
// ---------------------------------------------------------------------------
__global__ __launch_bounds__(256) void fused_fallback(
    const float* __restrict__ emb, const float* __restrict__ temp,
    const float* __restrict__ W1, const float* __restrict__ b1,
    const float* __restrict__ W2, const float* __restrict__ b2,
    const float* __restrict__ W3, const float* __restrict__ b3,
    const float* __restrict__ W4, const float* __restrict__ b4,
    float* __restrict__ out)
{
    __shared__ __align__(16) float FT[4][32][68];
    __shared__ __align__(16) float X[16][192];
    __shared__ __align__(16) float H[16][64];
    __shared__ __align__(16) float P[16][32];

    const int t = threadIdx.x;
    const int bx = blockIdx.x;
    const int b = bx / NTRI;
    int tidx = bx % NTRI;
    int ti = 0;
    while (tidx >= NT - ti) { tidx -= NT - ti; ++ti; }
    const int tj = ti + tidx;

    for (int ch = 0; ch < 8; ++ch) {
        const int tile = (ch < 4) ? ti : tj;
        const int sub = ch & 3;
        const int half = ch >> 2;
        const int rowbase = b * NROW + tile * 64 + sub * 16;
#pragma unroll
        for (int rep = 0; rep < 3; ++rep) {
            const int idx = t + rep * 256;
            const int r = idx / 48;
            const int c = idx - r * 48;
            float4 v;
            if (c < 32) v = reinterpret_cast<const float4*>(emb)[(size_t)(rowbase + r) * 32 + c];
            else        v = reinterpret_cast<const float4*>(temp)[(size_t)(rowbase + r) * 16 + (c - 32)];
            *reinterpret_cast<float4*>(&X[r][c * 4]) = v;
        }
        __syncthreads();
        {
            const int o = t & 63;
            const int r0 = t >> 6;
            float s0 = b1[o], s1 = s0, s2 = s0, s3 = s0;
#pragma unroll 4
            for (int k4 = 0; k4 < 48; ++k4) {
                const float4 x0 = *reinterpret_cast<const float4*>(&X[r0][k4 * 4]);
                const float4 x1 = *reinterpret_cast<const float4*>(&X[r0 + 4][k4 * 4]);
                const float4 x2 = *reinterpret_cast<const float4*>(&X[r0 + 8][k4 * 4]);
                const float4 x3 = *reinterpret_cast<const float4*>(&X[r0 + 12][k4 * 4]);
                const float w0 = W1[(k4 * 4 + 0) * 64 + o];
                const float w1 = W1[(k4 * 4 + 1) * 64 + o];
                const float w2 = W1[(k4 * 4 + 2) * 64 + o];
                const float w3 = W1[(k4 * 4 + 3) * 64 + o];
                s0 = fmaf(x0.w, w3, fmaf(x0.z, w2, fmaf(x0.y, w1, fmaf(x0.x, w0, s0))));
                s1 = fmaf(x1.w, w3, fmaf(x1.z, w2, fmaf(x1.y, w1, fmaf(x1.x, w0, s1))));
                s2 = fmaf(x2.w, w3, fmaf(x2.z, w2, fmaf(x2.y, w1, fmaf(x2.x, w0, s2))));
                s3 = fmaf(x3.w, w3, fmaf(x3.z, w2, fmaf(x3.y, w1, fmaf(x3.x, w0, s3))));
            }
            H[r0][o] = fmaxf(s0, 0.f);
            H[r0 + 4][o] = fmaxf(s1, 0.f);
            H[r0 + 8][o] = fmaxf(s2, 0.f);
            H[r0 + 12][o] = fmaxf(s3, 0.f);
        }
        __syncthreads();
        {
            const int o2 = t & 31;
            const int r8 = t >> 5;
#pragma unroll
            for (int rr = 0; rr < 2; ++rr) {
                const int r = r8 + rr * 8;
                float s = b2[o2];
#pragma unroll 8
                for (int k = 0; k < 64; ++k) s += H[r][k] * W2[k * 32 + o2];
                P[r][o2] = fmaxf(s, 0.f);
            }
        }
        __syncthreads();
        {
            const int o2 = t & 31;
            const int r8 = t >> 5;
#pragma unroll
            for (int rr = 0; rr < 2; ++rr) {
                const int r = r8 + rr * 8;
                float sa = 0.f, sb = b3[o2];
#pragma unroll 8
                for (int k = 0; k < 32; ++k) {
                    const float p = P[r][k];
                    sa += p * W3[k * 32 + o2];
                    sb += p * W3[(32 + k) * 32 + o2];
                }
                FT[half * 2 + 0][o2][sub * 16 + r] = sa;
                FT[half * 2 + 1][o2][sub * 16 + r] = sb;
            }
        }
        __syncthreads();
    }

    const int ty = t >> 4;
    const int tx = t & 15;
    float F[4][4] = {};
    float G[4][4] = {};
#pragma unroll
    for (int k = 0; k < 32; ++k) {
        const float w = W4[k];
        const float4 ai = *reinterpret_cast<const float4*>(&FT[0][k][4 * ty]);
        const float4 bi = *reinterpret_cast<const float4*>(&FT[1][k][4 * ty]);
        const float4 aj = *reinterpret_cast<const float4*>(&FT[2][k][4 * tx]);
        const float4 bj = *reinterpret_cast<const float4*>(&FT[3][k][4 * tx]);
        const float av[4] = {ai.x, ai.y, ai.z, ai.w};
        const float bw[4] = {bi.x, bi.y, bi.z, bi.w};
        const float aw[4] = {aj.x, aj.y, aj.z, aj.w};
        const float bv[4] = {bj.x, bj.y, bj.z, bj.w};
#pragma unroll
        for (int a = 0; a < 4; ++a)
#pragma unroll
            for (int c = 0; c < 4; ++c) {
                F[a][c] = fmaf(fmaxf(av[a] + bv[c], 0.f), w, F[a][c]);
                G[a][c] = fmaf(fmaxf(aw[c] + bw[a], 0.f), w, G[a][c]);
            }
    }
    const float bb = *b4;
    float S[4][4];
#pragma unroll
    for (int a = 0; a < 4; ++a)
#pragma unroll
        for (int c = 0; c < 4; ++c)
            S[a][c] = 0.5f * (tanh_fast(F[a][c] + bb) + tanh_fast(G[a][c] + bb));
    float* outb = out + (size_t)b * (NROW * NROW);
    const int i0 = ti * 64 + 4 * ty;
    const int j0 = tj * 64 + 4 * tx;
#pragma unroll
    for (int a = 0; a < 4; ++a) {
        float4 v = make_float4(S[a][0], S[a][1], S[a][2], S[a][3]);
        *reinterpret_cast<float4*>(&outb[(size_t)(i0 + a) * NROW + j0]) = v;
    }
    if (ti != tj) {
#pragma unroll
        for (int c = 0; c < 4; ++c) {
            float4 v = make_float4(S[0][c], S[1][c], S[2][c], S[3][c]);
            *reinterpret_cast<float4*>(&outb[(size_t)(j0 + c) * NROW + i0]) = v;
        }
    }
}

extern "C" void kernel_launch(void* const* d_in, const int* in_sizes, int n_in,
                              void* d_out, int out_size, void* d_ws, size_t ws_size,
                              hipStream_t stream) {
    const float* emb  = (const float*)d_in[0];
    const float* temp = (const float*)d_in[1];
    const float* W1   = (const float*)d_in[2];
    const float* b1   = (const float*)d_in[3];
    const float* W2   = (const float*)d_in[4];
    const float* b2   = (const float*)d_in[5];
    const float* W3   = (const float*)d_in[6];
    const float* b3   = (const float*)d_in[7];
    const float* W4   = (const float*)d_in[8];
    const float* b4   = (const float*)d_in[9];
    float* out = (float*)d_out;

    const size_t need = (size_t)2 * NROWS_TOT * 32 * sizeof(float);
    if (ws_size >= need) {
        float* hiS  = (float*)d_ws;
        float* hjbS = hiS + (size_t)NROWS_TOT * 32;
        hipLaunchKernelGGL(k_feat, dim3(NPROD), dim3(256), 0, stream,
                           emb, temp, W1, b1, W2, b2, W3, b3, hiS, hjbS);
        hipLaunchKernelGGL(k_pair, dim3(NBLK), dim3(256), 0, stream,
                           hiS, hjbS, W4, b4, out);
    } else {
        hipLaunchKernelGGL(fused_fallback, dim3(NBLK), dim3(256), 0, stream,
                           emb, temp, W1, b1, W2, b2, W3, b3, W4, b4, out);
    }
}